// Round 14
// baseline (346.486 us; speedup 1.0000x reference)
//
#include <hip/hip_runtime.h>
#include <hip/hip_bf16.h>
#include <math.h>
#include <type_traits>

constexpr int B = 2, C = 256, H = 64, W = 64, HW = H * W;
constexpr int N = 2048, OUT = 7, P = 49, FD = C * P; // 12544
constexpr int K1 = 1024;
constexpr float CLAMP_V = 4.135f, SCALE_V = 1.0f / 16.0f;
constexpr int LDB = 264; // conv LDS row stride (bf16 elems)

typedef short s8v __attribute__((ext_vector_type(8)));   // 8 bf16 (4 VGPRs)
typedef short s4v __attribute__((ext_vector_type(4)));   // 4 bf16
typedef float f32x4 __attribute__((ext_vector_type(4))); // MFMA C/D fragment

template <int I, int NN, class F>
__device__ __forceinline__ void static_for(F&& f) {
    if constexpr (I < NN) {
        f(std::integral_constant<int, I>{});
        static_for<I + 1, NN>(static_cast<F&&>(f));
    }
}

// bijective XCD-chunk swizzle (requires nblk % 8 == 0)
__device__ __forceinline__ int xcd_swz(int blk, int nblk) {
    const int cpx = nblk >> 3;
    return (blk & 7) * cpx + (blk >> 3);
}

// ---- K-prep (merged): transpose_feat | wB | aw | fc1B | fc2B ----
__global__ void k_prep_all(const float* __restrict__ features, float* __restrict__ featT,
                           const float* __restrict__ conv_w, __hip_bfloat16* __restrict__ wB,
                           const float* __restrict__ align_w, float4* __restrict__ aw4,
                           float* __restrict__ aw1,
                           const float* __restrict__ fc1_w, __hip_bfloat16* __restrict__ fc1B,
                           const float* __restrict__ fc2_w, __hip_bfloat16* __restrict__ fc2B) {
    __shared__ float smem[64 * 49]; // 12.25 KB, reused per branch
    const int id = blockIdx.x;
    const int t = threadIdx.x;
    if (id < 2048) {
        const int x = id % 128, y = (id / 128) % 8, b = id / 1024;
        const int c0 = y * 32, p0 = x * 32;
        const int tx = t % 32, ty = t / 32;
        float* tile = smem; // [32][33]
#pragma unroll
        for (int r = 0; r < 32; r += 8)
            tile[(ty + r) * 33 + tx] = features[(size_t)(b * C + c0 + ty + r) * HW + p0 + tx];
        __syncthreads();
#pragma unroll
        for (int r = 0; r < 32; r += 8)
            featT[(size_t)(b * HW + p0 + ty + r) * C + c0 + tx] = tile[tx * 33 + ty + r];
    } else if (id < 2120) {
        const int T = id - 2048;
        const int tap = T / 8, s = T % 8;
        const int co = t;
#pragma unroll
        for (int q = 0; q < 4; ++q)
#pragma unroll
            for (int j = 0; j < 8; ++j) {
                const int ci = s * 32 + q * 8 + j;
                wB[(((size_t)T * 256 + co) * 4 + q) * 8 + j] =
                    __float2bfloat16(conv_w[(size_t)co * 2304 + ci * 9 + tap]);
            }
    } else if (id < 2169) {
        const int o = id - 2120;
        const int co = t;
        float4 v;
        v.x = align_w[(size_t)0 * FD + co * 49 + o];
        v.y = align_w[(size_t)1 * FD + co * 49 + o];
        v.z = align_w[(size_t)2 * FD + co * 49 + o];
        v.w = align_w[(size_t)3 * FD + co * 49 + o];
        aw4[o * 256 + co] = v;
        aw1[o * 256 + co] = align_w[(size_t)4 * FD + co * 49 + o];
    } else if (id < 6265) {
        const int q = id - 2169;
        const int c0 = (q % 4) * 64;
        const int o = q / 4;
        const float* src = fc1_w + (size_t)o * FD + (size_t)c0 * 49;
        for (int i = t; i < 64 * 49; i += 256) smem[i] = src[i];
        __syncthreads();
        __hip_bfloat16* dst = fc1B + (size_t)o * FD + c0;
        for (int j = t; j < 64 * 49; j += 256) {
            const int p = j >> 6, cc = j & 63;
            dst[(size_t)p * 256 + cc] = __float2bfloat16(smem[cc * 49 + p]);
        }
    } else {
        const int bid = id - 6265;
        const int n4 = (K1 * K1) / 4;
        for (int i = bid * 256 + t; i < n4; i += 256 * 256) {
            const float4 v = reinterpret_cast<const float4*>(fc2_w)[i];
            fc2B[i * 4 + 0] = __float2bfloat16(v.x);
            fc2B[i * 4 + 1] = __float2bfloat16(v.y);
            fc2B[i * 4 + 2] = __float2bfloat16(v.z);
            fc2B[i * 4 + 3] = __float2bfloat16(v.w);
        }
    }
}

// ------- K2: mega kernel, 1 RoI/block (small LDS footprint -> ~6 blocks/CU) -------
__global__ void k_roi_conv_grid(
    const float* __restrict__ featT, const float* __restrict__ proposals,
    const int* __restrict__ bidx, const __hip_bfloat16* __restrict__ wB,
    const float* __restrict__ conv_b, const float4* __restrict__ aw4,
    const float* __restrict__ aw1, const float* __restrict__ align_b,
    __hip_bfloat16* __restrict__ alignedOut) {
    __shared__ __align__(16) __hip_bfloat16 bfh[50 * LDB]; // rows 0..48; row 49 = zeros
    __shared__ float red[44]; // [0..19] wave partials; [40..43] grid params

    const int n = xcd_swz(blockIdx.x, 2048);
    const int t = threadIdx.x;
    const int lane = t & 63, wid = t >> 6;
    const int l15 = lane & 15;
    const int qofs = (lane >> 4) * 8;

    // ---- phase 1: roi_align, wave=bin, lane=4 channels, float4 loads ----
    {
        const float px1 = proposals[n * 4 + 0] * SCALE_V, py1 = proposals[n * 4 + 1] * SCALE_V;
        const float px2 = proposals[n * 4 + 2] * SCALE_V, py2 = proposals[n * 4 + 3] * SCALE_V;
        const float bw = fmaxf(px2 - px1, 1.0f) * (1.0f / OUT);
        const float bh = fmaxf(py2 - py1, 1.0f) * (1.0f / OUT);
        const int b = bidx[n];
        const float* fb = featT + (size_t)b * HW * C;
        for (int p = wid; p < P; p += 4) {              // wave-uniform bin
            const int pyi = p / 7, pxi = p % 7;
            float y = py1 + (pyi + 0.5f) * bh;
            float x = px1 + (pxi + 0.5f) * bw;
            y = fminf(fmaxf(y, 0.f), (float)(H - 1));
            x = fminf(fmaxf(x, 0.f), (float)(W - 1));
            const float y0f = floorf(y), x0f = floorf(x);
            const int y0 = (int)y0f, x0 = (int)x0f;
            const int y1 = min(y0 + 1, H - 1), x1 = min(x0 + 1, W - 1);
            const float wy1 = y - y0f, wx1 = x - x0f;
            const float wy0 = 1.f - wy1, wx0 = 1.f - wx1;
            const int c4 = lane * 4;
            const float4 v00 = *reinterpret_cast<const float4*>(&fb[(size_t)(y0 * W + x0) * C + c4]);
            const float4 v01 = *reinterpret_cast<const float4*>(&fb[(size_t)(y0 * W + x1) * C + c4]);
            const float4 v10 = *reinterpret_cast<const float4*>(&fb[(size_t)(y1 * W + x0) * C + c4]);
            const float4 v11 = *reinterpret_cast<const float4*>(&fb[(size_t)(y1 * W + x1) * C + c4]);
            s4v o4;
            o4[0] = (short)__bfloat16_as_ushort(__float2bfloat16(
                        wy0 * (wx0 * v00.x + wx1 * v01.x) + wy1 * (wx0 * v10.x + wx1 * v11.x)));
            o4[1] = (short)__bfloat16_as_ushort(__float2bfloat16(
                        wy0 * (wx0 * v00.y + wx1 * v01.y) + wy1 * (wx0 * v10.y + wx1 * v11.y)));
            o4[2] = (short)__bfloat16_as_ushort(__float2bfloat16(
                        wy0 * (wx0 * v00.z + wx1 * v01.z) + wy1 * (wx0 * v10.z + wx1 * v11.z)));
            o4[3] = (short)__bfloat16_as_ushort(__float2bfloat16(
                        wy0 * (wx0 * v00.w + wx1 * v01.w) + wy1 * (wx0 * v10.w + wx1 * v11.w)));
            *reinterpret_cast<s4v*>(&bfh[p * LDB + c4]) = o4;
        }
    }
    bfh[49 * LDB + t] = __float2bfloat16(0.f); // zero row for invalid taps / pad rows
    __syncthreads();

    // ---- phase 2: conv as 9 shift-GEMMs, M = 49 (4 tiles of 16, pad -> zero row) ----
    int oyt[4], oxt[4];
    bool pval[4];
    static_for<0, 4>([&](auto MT) {
        const int p = MT.value * 16 + l15;
        pval[MT.value] = (p < 49);
        oyt[MT.value] = p / 7;
        oxt[MT.value] = p % 7;
    });
    int bofs[4];
    static_for<0, 4>([&](auto NT) {
        const int col = wid * 64 + NT.value * 16 + l15;
        bofs[NT.value] = col * 32 + qofs;
    });

    f32x4 acc[4][4] = {};
    for (int tap = 0; tap < 9; ++tap) {
        const int dy = tap / 3 - 1, dx = tap % 3 - 1;
        int rsel[4];
        static_for<0, 4>([&](auto MT) {
            const int iy = oyt[MT.value] + dy, ix = oxt[MT.value] + dx;
            const bool v = pval[MT.value] && ((unsigned)iy < 7u) && ((unsigned)ix < 7u);
            rsel[MT.value] = (v ? (iy * 7 + ix) : 49) * LDB;
        });
        const __hip_bfloat16* wTap = wB + (size_t)tap * 8 * 8192;
#pragma unroll
        for (int s = 0; s < 8; ++s) {
            s8v af[4], bfr[4];
            static_for<0, 4>([&](auto NT) {
                bfr[NT.value] = *reinterpret_cast<const s8v*>(&wTap[(size_t)s * 8192 + bofs[NT.value]]);
            });
            static_for<0, 4>([&](auto MT) {
                af[MT.value] = *reinterpret_cast<const s8v*>(&bfh[rsel[MT.value] + s * 32 + qofs]);
            });
            __builtin_amdgcn_s_setprio(1);
            static_for<0, 4>([&](auto MT) {
                static_for<0, 4>([&](auto NT) {
                    acc[MT.value][NT.value] = __builtin_amdgcn_mfma_f32_16x16x32_bf16(
                        af[MT.value], bfr[NT.value], acc[MT.value][NT.value], 0, 0, 0);
                });
            });
            __builtin_amdgcn_s_setprio(0);
        }
    }

    // ---- phase 3: bias+relu+align GEMV on D fragments ----
    const int hi = lane >> 4;
    float cb[4];
    static_for<0, 4>([&](auto NT) { cb[NT.value] = conv_b[wid * 64 + NT.value * 16 + l15]; });
    float pc[5] = {};
    static_for<0, 4>([&](auto MT) {
        static_for<0, 4>([&](auto RR) {
            const int o = MT.value * 16 + hi * 4 + RR.value;
            if (o < 49) {
                static_for<0, 4>([&](auto NT) {
                    const int co = wid * 64 + NT.value * 16 + l15;
                    const float4 w4 = aw4[o * 256 + co];
                    const float  w1 = aw1[o * 256 + co];
                    const float a = fmaxf(acc[MT.value][NT.value][RR.value] + cb[NT.value], 0.f);
                    pc[0] = fmaf(a, w4.x, pc[0]);
                    pc[1] = fmaf(a, w4.y, pc[1]);
                    pc[2] = fmaf(a, w4.z, pc[2]);
                    pc[3] = fmaf(a, w4.w, pc[3]);
                    pc[4] = fmaf(a, w1,   pc[4]);
                });
            }
        });
    });
    static_for<0, 5>([&](auto J) {
        float s = pc[J.value];
#pragma unroll
        for (int off = 32; off; off >>= 1) s += __shfl_xor(s, off);
        pc[J.value] = s;
    });
    if (lane == 0) {
        static_for<0, 5>([&](auto J) { red[wid * 5 + J.value] = pc[J.value]; });
    }
    __syncthreads();

    // ---- phase 4: decode -> grid params (thread 0) ----
    if (t == 0) {
        float coarse[5];
        static_for<0, 5>([&](auto Jc) {
            constexpr int j = Jc.value;
            float s = red[j] + red[5 + j] + red[10 + j] + red[15 + j] + align_b[j];
            coarse[j] = fminf(fmaxf(s, -CLAMP_V), CLAMP_V);
        });
        const float x1r = proposals[n * 4 + 0], y1r = proposals[n * 4 + 1];
        const float x2r = proposals[n * 4 + 2], y2r = proposals[n * 4 + 3];
        const float w = x2r - x1r, h = y2r - y1r;
        const float w2 = w * expf(coarse[2]);
        const float h2 = h * expf(coarse[3]);
        const float ang = coarse[4];
        const float cth = cosf(ang), sth = sinf(ang);
        const float sx = w2 * (1.0f / OUT), sy = h2 * (1.0f / OUT);
        red[40] = sx * cth;
        red[41] = sy * sth;
        red[42] = sx * sth;
        red[43] = sy * cth;
    }
    __syncthreads();

    // ---- phase 5: grid_sample(zeros), vectorized x4: wave-uniform p, lane = 4 channels ----
    {
        const float gA = red[40], gBv = red[41], gC = red[42], gD = red[43];
        __hip_bfloat16* ao = alignedOut + (size_t)n * FD;
        const int c4 = lane * 4;
        for (int p = wid; p < P; p += 4) {             // wave-uniform bin
            const int pyi = p / 7, pxi = p % 7;
            const float xb = (2 * pxi + 1) * (1.0f / OUT) - 1.0f;
            const float yb = (2 * pyi + 1) * (1.0f / OUT) - 1.0f;
            const float gx = gA * xb - gBv * yb;
            const float gy = gC * xb + gD * yb;
            const float ix = ((gx + 1.0f) * OUT - 1.0f) * 0.5f;
            const float iy = ((gy + 1.0f) * OUT - 1.0f) * 0.5f;
            const float x0f = floorf(ix), y0f = floorf(iy);
            const int x0 = (int)x0f, y0 = (int)y0f;
            const float wx1 = ix - x0f, wy1 = iy - y0f;
            const float wx0 = 1.f - wx1, wy0 = 1.f - wy1;
            const float w00 = wy0 * wx0, w01 = wy0 * wx1, w10 = wy1 * wx0, w11 = wy1 * wx1;
            const bool vx0 = (unsigned)x0 < 7u, vx1 = (unsigned)(x0 + 1) < 7u;
            const bool vy0 = (unsigned)y0 < 7u, vy1 = (unsigned)(y0 + 1) < 7u;
            const int r00 = (vy0 && vx0) ? (y0 * 7 + x0) : 49;       // row 49 = zeros
            const int r01 = (vy0 && vx1) ? (y0 * 7 + x0 + 1) : 49;
            const int r10 = (vy1 && vx0) ? ((y0 + 1) * 7 + x0) : 49;
            const int r11 = (vy1 && vx1) ? ((y0 + 1) * 7 + x0 + 1) : 49;
            const s4v b00 = *reinterpret_cast<const s4v*>(&bfh[r00 * LDB + c4]);
            const s4v b01 = *reinterpret_cast<const s4v*>(&bfh[r01 * LDB + c4]);
            const s4v b10 = *reinterpret_cast<const s4v*>(&bfh[r10 * LDB + c4]);
            const s4v b11 = *reinterpret_cast<const s4v*>(&bfh[r11 * LDB + c4]);
            s4v o4;
            static_for<0, 4>([&](auto J) {
                constexpr int j = J.value;
                float v = w00 * __bfloat162float(__ushort_as_bfloat16((unsigned short)b00[j]))
                        + w01 * __bfloat162float(__ushort_as_bfloat16((unsigned short)b01[j]))
                        + w10 * __bfloat162float(__ushort_as_bfloat16((unsigned short)b10[j]))
                        + w11 * __bfloat162float(__ushort_as_bfloat16((unsigned short)b11[j]));
                o4[j] = (short)__bfloat16_as_ushort(__float2bfloat16(v));
            });
            *reinterpret_cast<s4v*>(&ao[p * 256 + c4]) = o4;
        }
    }
}

// ---- K3/K4: bf16 MFMA GEMM, BM=BN=BK=64, 4 blocks/CU target ----
template <int BM, int BN, int BK>
__global__ __launch_bounds__(256, 4) void k_gemm_bf16(
    const __hip_bfloat16* __restrict__ A, const __hip_bfloat16* __restrict__ Wt,
    const float* __restrict__ bias, float* __restrict__ CoutF,
    __hip_bfloat16* __restrict__ CoutH, int M, int Nn, int K, int relu) {
    constexpr int LD = BK + 8; // 72 halfwords
    __shared__ __align__(16) __hip_bfloat16 As[2][BM * LD];
    __shared__ __align__(16) __hip_bfloat16 Ws[2][BN * LD];
    const int ntb = Nn / BN;
    const int blkS = xcd_swz(blockIdx.x, gridDim.x);
    const int bx = blkS % ntb, by = blkS / ntb;
    const int t = threadIdx.x;
    const int lane = t & 63, wid = t >> 6;
    const int l15 = lane & 15;
    const int qofs = (lane >> 4) * 8;
    const int wm = wid >> 1, wn = wid & 1;

    const int ar = t >> 3, ak = (t & 7) * 8;
    const size_t aBase = (size_t)(by * BM) * K;
    const size_t bBase = (size_t)(bx * BN) * K;

    f32x4 acc[2][2] = {};

    const int steps = K / BK;
    {
        const s8v a0 = *reinterpret_cast<const s8v*>(&A[aBase + (size_t)ar * K + ak]);
        const s8v a1 = *reinterpret_cast<const s8v*>(&A[aBase + (size_t)(ar + 32) * K + ak]);
        const s8v b0 = *reinterpret_cast<const s8v*>(&Wt[bBase + (size_t)ar * K + ak]);
        const s8v b1 = *reinterpret_cast<const s8v*>(&Wt[bBase + (size_t)(ar + 32) * K + ak]);
        *reinterpret_cast<s8v*>(&As[0][ar * LD + ak]) = a0;
        *reinterpret_cast<s8v*>(&As[0][(ar + 32) * LD + ak]) = a1;
        *reinterpret_cast<s8v*>(&Ws[0][ar * LD + ak]) = b0;
        *reinterpret_cast<s8v*>(&Ws[0][(ar + 32) * LD + ak]) = b1;
    }
    __syncthreads();

    for (int s = 0; s < steps; ++s) {
        const int cur = s & 1;
        const bool pf = (s + 1 < steps);
        s8v a0, a1, b0, b1;
        if (pf) {
            const int k0 = (s + 1) * BK;
            a0 = *reinterpret_cast<const s8v*>(&A[aBase + (size_t)ar * K + k0 + ak]);
            a1 = *reinterpret_cast<const s8v*>(&A[aBase + (size_t)(ar + 32) * K + k0 + ak]);
            b0 = *reinterpret_cast<const s8v*>(&Wt[bBase + (size_t)ar * K + k0 + ak]);
            b1 = *reinterpret_cast<const s8v*>(&Wt[bBase + (size_t)(ar + 32) * K + k0 + ak]);
        }
        static_for<0, 2>([&](auto KH) {
            s8v afr[2], bfr[2];
            static_for<0, 2>([&](auto MT) {
                afr[MT.value] = *reinterpret_cast<const s8v*>(
                    &As[cur][(wm * 32 + MT.value * 16 + l15) * LD + KH.value * 32 + qofs]);
            });
            static_for<0, 2>([&](auto NT) {
                bfr[NT.value] = *reinterpret_cast<const s8v*>(
                    &Ws[cur][(wn * 32 + NT.value * 16 + l15) * LD + KH.value * 32 + qofs]);
            });
            static_for<0, 2>([&](auto MT) {
                static_for<0, 2>([&](auto NT) {
                    acc[MT.value][NT.value] = __builtin_amdgcn_mfma_f32_16x16x32_bf16(
                        afr[MT.value], bfr[NT.value], acc[MT.value][NT.value], 0, 0, 0);
                });
            });
        });
        if (pf) {
            __syncthreads();
            const int nxt = cur ^ 1;
            *reinterpret_cast<s8v*>(&As[nxt][ar * LD + ak]) = a0;
            *reinterpret_cast<s8v*>(&As[nxt][(ar + 32) * LD + ak]) = a1;
            *reinterpret_cast<s8v*>(&Ws[nxt][ar * LD + ak]) = b0;
            *reinterpret_cast<s8v*>(&Ws[nxt][(ar + 32) * LD + ak]) = b1;
            __syncthreads();
        }
    }

    static_for<0, 2>([&](auto MT) {
        static_for<0, 2>([&](auto NT) {
            const int col = bx * BN + wn * 32 + NT.value * 16 + l15;
            const float bv = bias[col];
            static_for<0, 4>([&](auto RR) {
                const int row = by * BM + wm * 32 + MT.value * 16 + (lane >> 4) * 4 + RR.value;
                float v = acc[MT.value][NT.value][RR.value] + bv;
                if (relu) v = fmaxf(v, 0.f);
                if (CoutF) CoutF[(size_t)row * Nn + col] = v;
                if (CoutH) CoutH[(size_t)row * Nn + col] = __float2bfloat16(v);
            });
        });
    });
}

// ---------------- K5: heads (cls/box GEMV + softmax + decode) ----------------
__global__ void k_heads(const float* __restrict__ r2, const float* __restrict__ cls_w,
                        const float* __restrict__ cls_b, const float* __restrict__ box_w,
                        const float* __restrict__ box_b, const float* __restrict__ proposals,
                        float* __restrict__ out) {
    const int n = blockIdx.x;
    const int t = threadIdx.x; // 64 lanes
    const float* r = r2 + (size_t)n * K1;
    float rv[16];
    static_for<0, 16>([&](auto Jc) { rv[Jc.value] = r[t + 64 * Jc.value]; });
    float s[21];
    static_for<0, 21>([&](auto Oc) {
        constexpr int o = Oc.value;
        const float* w = (o < 16) ? (cls_w + (size_t)o * K1) : (box_w + (size_t)(o - 16) * K1);
        float a = 0.f;
        static_for<0, 16>([&](auto Jc) { a = fmaf(rv[Jc.value], w[t + 64 * Jc.value], a); });
#pragma unroll
        for (int off = 32; off; off >>= 1) a += __shfl_xor(a, off);
        s[o] = a;
    });
    float logits[16];
    float m = -1e30f;
    static_for<0, 16>([&](auto Oc) {
        logits[Oc.value] = s[Oc.value] + cls_b[Oc.value];
        m = fmaxf(m, logits[Oc.value]);
    });
    float es = 0.f;
    static_for<0, 16>([&](auto Oc) {
        logits[Oc.value] = expf(logits[Oc.value] - m);
        es += logits[Oc.value];
    });
    const float inv = 1.0f / es;
    float fdelta[5];
    static_for<0, 5>([&](auto Jc) {
        fdelta[Jc.value] = fminf(fmaxf(s[16 + Jc.value] + box_b[Jc.value], -CLAMP_V), CLAMP_V);
    });
    const float x1r = proposals[n * 4 + 0], y1r = proposals[n * 4 + 1];
    const float x2r = proposals[n * 4 + 2], y2r = proposals[n * 4 + 3];
    const float cx = (x1r + x2r) * 0.5f, cy = (y1r + y2r) * 0.5f;
    const float w = x2r - x1r, h = y2r - y1r;
    float pred[5];
    pred[0] = cx + fdelta[0] * w;
    pred[1] = cy + fdelta[1] * h;
    pred[2] = w * expf(fdelta[2]);
    pred[3] = h * expf(fdelta[3]);
    pred[4] = fdelta[4];
    float* orow = out + (size_t)n * 21;
    static_for<0, 5>([&](auto Oc) {
        if (t == Oc.value) orow[Oc.value] = pred[Oc.value];
    });
    static_for<0, 16>([&](auto Oc) {
        if (t == 5 + Oc.value) orow[5 + Oc.value] = logits[Oc.value] * inv;
    });
}

extern "C" void kernel_launch(void* const* d_in, const int* in_sizes, int n_in,
                              void* d_out, int out_size, void* d_ws, size_t ws_size,
                              hipStream_t stream) {
    (void)in_sizes; (void)n_in; (void)out_size; (void)ws_size;
    const float* features  = (const float*)d_in[0];
    const float* proposals = (const float*)d_in[1];
    const int*   batch_idx = (const int*)d_in[2];
    const float* conv_w    = (const float*)d_in[3];
    const float* conv_b    = (const float*)d_in[4];
    const float* align_w   = (const float*)d_in[5];
    const float* align_b   = (const float*)d_in[6];
    const float* fc1_w     = (const float*)d_in[7];
    const float* fc1_b     = (const float*)d_in[8];
    const float* fc2_w     = (const float*)d_in[9];
    const float* fc2_b     = (const float*)d_in[10];
    const float* cls_w     = (const float*)d_in[11];
    const float* cls_b     = (const float*)d_in[12];
    const float* box_w     = (const float*)d_in[13];
    const float* box_b     = (const float*)d_in[14];
    float* out = (float*)d_out;

    float* ws    = (float*)d_ws;
    float* featT = ws;                           //  2,097,152 f
    float* r2    = featT + (size_t)B * HW * C;   //  2,097,152 f
    float4* aw4  = (float4*)(r2 + (size_t)N * K1);   // 49*256 float4
    float* aw1   = (float*)(aw4 + 49 * 256);         // 12,544 f
    __hip_bfloat16* alignedH = (__hip_bfloat16*)(aw1 + 49 * 256); // 25,690,112 h
    __hip_bfloat16* r1H   = alignedH + (size_t)N * FD;   //  2,097,152 h
    __hip_bfloat16* wB    = r1H + (size_t)N * K1;        //    589,824 h
    __hip_bfloat16* fc1B  = wB + 2304 * 256;             // 12,845,056 h
    __hip_bfloat16* fc2B  = fc1B + (size_t)K1 * FD;      //  1,048,576 h

    k_prep_all<<<6521, 256, 0, stream>>>(features, featT, conv_w, wB, align_w, aw4, aw1,
                                         fc1_w, fc1B, fc2_w, fc2B);
    k_roi_conv_grid<<<N, 256, 0, stream>>>(featT, proposals, batch_idx, wB, conv_b,
                                           aw4, aw1, align_b, alignedH);
    k_gemm_bf16<64, 64, 64><<<(N / 64) * (K1 / 64), 256, 0, stream>>>(
        alignedH, fc1B, fc1_b, nullptr, r1H, N, K1, FD, 1);
    k_gemm_bf16<64, 64, 64><<<(N / 64) * (K1 / 64), 256, 0, stream>>>(
        r1H, fc2B, fc2_b, r2, nullptr, N, K1, K1, 1);
    k_heads<<<N, 64, 0, stream>>>(r2, cls_w, cls_b, box_w, box_b, proposals, out);
}

// Round 15
// 301.263 us; speedup vs baseline: 1.1501x; 1.1501x over previous
//
#include <hip/hip_runtime.h>
#include <hip/hip_bf16.h>
#include <math.h>
#include <type_traits>

constexpr int B = 2, C = 256, H = 64, W = 64, HW = H * W;
constexpr int N = 2048, OUT = 7, P = 49, FD = C * P; // 12544
constexpr int K1 = 1024;
constexpr float CLAMP_V = 4.135f, SCALE_V = 1.0f / 16.0f;
constexpr int LDB = 264; // conv LDS row stride (bf16); 528B: 4-bank row advance = min 2-way

typedef short s8v __attribute__((ext_vector_type(8)));   // 8 bf16 (4 VGPRs)
typedef short s4v __attribute__((ext_vector_type(4)));   // 4 bf16
typedef float f32x4 __attribute__((ext_vector_type(4))); // MFMA C/D fragment

template <int I, int NN, class F>
__device__ __forceinline__ void static_for(F&& f) {
    if constexpr (I < NN) {
        f(std::integral_constant<int, I>{});
        static_for<I + 1, NN>(static_cast<F&&>(f));
    }
}

// bijective XCD-chunk swizzle (requires nblk % 8 == 0)
__device__ __forceinline__ int xcd_swz(int blk, int nblk) {
    const int cpx = nblk >> 3;
    return (blk & 7) * cpx + (blk >> 3);
}

// ---- K-prep (merged): transpose_feat | wB | aw | fc1B | fc2B ----
__global__ void k_prep_all(const float* __restrict__ features, float* __restrict__ featT,
                           const float* __restrict__ conv_w, __hip_bfloat16* __restrict__ wB,
                           const float* __restrict__ align_w, float4* __restrict__ aw4,
                           float* __restrict__ aw1,
                           const float* __restrict__ fc1_w, __hip_bfloat16* __restrict__ fc1B,
                           const float* __restrict__ fc2_w, __hip_bfloat16* __restrict__ fc2B) {
    __shared__ float smem[64 * 49]; // 12.25 KB, reused per branch
    const int id = blockIdx.x;
    const int t = threadIdx.x;
    if (id < 2048) {
        const int x = id % 128, y = (id / 128) % 8, b = id / 1024;
        const int c0 = y * 32, p0 = x * 32;
        const int tx = t % 32, ty = t / 32;
        float* tile = smem; // [32][33]
#pragma unroll
        for (int r = 0; r < 32; r += 8)
            tile[(ty + r) * 33 + tx] = features[(size_t)(b * C + c0 + ty + r) * HW + p0 + tx];
        __syncthreads();
#pragma unroll
        for (int r = 0; r < 32; r += 8)
            featT[(size_t)(b * HW + p0 + ty + r) * C + c0 + tx] = tile[tx * 33 + ty + r];
    } else if (id < 2120) {
        const int T = id - 2048;
        const int tap = T / 8, s = T % 8;
        const int co = t;
#pragma unroll
        for (int q = 0; q < 4; ++q)
#pragma unroll
            for (int j = 0; j < 8; ++j) {
                const int ci = s * 32 + q * 8 + j;
                wB[(((size_t)T * 256 + co) * 4 + q) * 8 + j] =
                    __float2bfloat16(conv_w[(size_t)co * 2304 + ci * 9 + tap]);
            }
    } else if (id < 2169) {
        const int o = id - 2120;
        const int co = t;
        float4 v;
        v.x = align_w[(size_t)0 * FD + co * 49 + o];
        v.y = align_w[(size_t)1 * FD + co * 49 + o];
        v.z = align_w[(size_t)2 * FD + co * 49 + o];
        v.w = align_w[(size_t)3 * FD + co * 49 + o];
        aw4[o * 256 + co] = v;
        aw1[o * 256 + co] = align_w[(size_t)4 * FD + co * 49 + o];
    } else if (id < 6265) {
        const int q = id - 2169;
        const int c0 = (q % 4) * 64;
        const int o = q / 4;
        const float* src = fc1_w + (size_t)o * FD + (size_t)c0 * 49;
        for (int i = t; i < 64 * 49; i += 256) smem[i] = src[i];
        __syncthreads();
        __hip_bfloat16* dst = fc1B + (size_t)o * FD + c0;
        for (int j = t; j < 64 * 49; j += 256) {
            const int p = j >> 6, cc = j & 63;
            dst[(size_t)p * 256 + cc] = __float2bfloat16(smem[cc * 49 + p]);
        }
    } else {
        const int bid = id - 6265;
        const int n4 = (K1 * K1) / 4;
        for (int i = bid * 256 + t; i < n4; i += 256 * 256) {
            const float4 v = reinterpret_cast<const float4*>(fc2_w)[i];
            fc2B[i * 4 + 0] = __float2bfloat16(v.x);
            fc2B[i * 4 + 1] = __float2bfloat16(v.y);
            fc2B[i * 4 + 2] = __float2bfloat16(v.z);
            fc2B[i * 4 + 3] = __float2bfloat16(v.w);
        }
    }
}

// ------- K2: per-block mega kernel, 2 RoIs/block, M-paired (row = 2p+r) -------
// NOTE: occupancy is register-pinned at 2 blocks/CU (acc 112 + arch 108 regs).
// (256,3) forces spill (r12: 679us); 1-RoI/block loses feed efficiency (r14: 202us).
__global__ __launch_bounds__(256, 2) void k_roi_conv_grid(
    const float* __restrict__ featT, const float* __restrict__ proposals,
    const int* __restrict__ bidx, const __hip_bfloat16* __restrict__ wB,
    const float* __restrict__ conv_b, const float4* __restrict__ aw4,
    const float* __restrict__ aw1, const float* __restrict__ align_b,
    __hip_bfloat16* __restrict__ alignedOut) {
    __shared__ __align__(16) __hip_bfloat16 bfh[100 * LDB]; // rows 2p+r; 98,99 = zeros
    __shared__ float red[64];

    const int blk = xcd_swz(blockIdx.x, 1024);
    const int t = threadIdx.x;
    const int lane = t & 63, wid = t >> 6;
    const int l15 = lane & 15;
    const int qofs = (lane >> 4) * 8;

    // ---- phase 1: roi_align, wave=bin, lane=4 channels, float4 loads ----
#pragma unroll
    for (int r = 0; r < 2; ++r) {
        const int n = blk * 2 + r;
        const float px1 = proposals[n * 4 + 0] * SCALE_V, py1 = proposals[n * 4 + 1] * SCALE_V;
        const float px2 = proposals[n * 4 + 2] * SCALE_V, py2 = proposals[n * 4 + 3] * SCALE_V;
        const float bw = fmaxf(px2 - px1, 1.0f) * (1.0f / OUT);
        const float bh = fmaxf(py2 - py1, 1.0f) * (1.0f / OUT);
        const int b = bidx[n];
        const float* fb = featT + (size_t)b * HW * C;
#pragma unroll 2
        for (int p = wid; p < P; p += 4) {              // wave-uniform bin
            const int pyi = p / 7, pxi = p % 7;
            float y = py1 + (pyi + 0.5f) * bh;
            float x = px1 + (pxi + 0.5f) * bw;
            y = fminf(fmaxf(y, 0.f), (float)(H - 1));
            x = fminf(fmaxf(x, 0.f), (float)(W - 1));
            const float y0f = floorf(y), x0f = floorf(x);
            const int y0 = (int)y0f, x0 = (int)x0f;
            const int y1 = min(y0 + 1, H - 1), x1 = min(x0 + 1, W - 1);
            const float wy1 = y - y0f, wx1 = x - x0f;
            const float wy0 = 1.f - wy1, wx0 = 1.f - wx1;
            const int c4 = lane * 4;
            const float4 v00 = *reinterpret_cast<const float4*>(&fb[(size_t)(y0 * W + x0) * C + c4]);
            const float4 v01 = *reinterpret_cast<const float4*>(&fb[(size_t)(y0 * W + x1) * C + c4]);
            const float4 v10 = *reinterpret_cast<const float4*>(&fb[(size_t)(y1 * W + x0) * C + c4]);
            const float4 v11 = *reinterpret_cast<const float4*>(&fb[(size_t)(y1 * W + x1) * C + c4]);
            s4v o4;
            o4[0] = (short)__bfloat16_as_ushort(__float2bfloat16(
                        wy0 * (wx0 * v00.x + wx1 * v01.x) + wy1 * (wx0 * v10.x + wx1 * v11.x)));
            o4[1] = (short)__bfloat16_as_ushort(__float2bfloat16(
                        wy0 * (wx0 * v00.y + wx1 * v01.y) + wy1 * (wx0 * v10.y + wx1 * v11.y)));
            o4[2] = (short)__bfloat16_as_ushort(__float2bfloat16(
                        wy0 * (wx0 * v00.z + wx1 * v01.z) + wy1 * (wx0 * v10.z + wx1 * v11.z)));
            o4[3] = (short)__bfloat16_as_ushort(__float2bfloat16(
                        wy0 * (wx0 * v00.w + wx1 * v01.w) + wy1 * (wx0 * v10.w + wx1 * v11.w)));
            *reinterpret_cast<s4v*>(&bfh[(2 * p + r) * LDB + c4]) = o4;
        }
    }
    bfh[98 * LDB + t] = __float2bfloat16(0.f);
    bfh[99 * LDB + t] = __float2bfloat16(0.f);
    __syncthreads();

    // ---- phase 2: conv as 9 shift-GEMMs, M = 98 interleaved rows (7 tiles) ----
    const int rp = l15 & 1; // row parity = RoI of this lane's A-rows
    int oyt[7], oxt[7];
    bool pval[7];
    static_for<0, 7>([&](auto MT) {
        const int p = (MT.value * 16 + l15) >> 1;
        pval[MT.value] = (p < 49);
        oyt[MT.value] = p / 7;
        oxt[MT.value] = p % 7;
    });
    int bofs[4];
    static_for<0, 4>([&](auto NT) {
        const int col = wid * 64 + NT.value * 16 + l15;
        bofs[NT.value] = col * 32 + qofs;
    });

    f32x4 acc[7][4] = {};
    for (int tap = 0; tap < 9; ++tap) {
        const int dy = tap / 3 - 1, dx = tap % 3 - 1;
        int rsel[7];
        static_for<0, 7>([&](auto MT) {
            const int iy = oyt[MT.value] + dy, ix = oxt[MT.value] + dx;
            const bool v = pval[MT.value] && ((unsigned)iy < 7u) && ((unsigned)ix < 7u);
            rsel[MT.value] = (v ? (2 * (iy * 7 + ix) + rp) : (98 + rp)) * LDB;
        });
        const __hip_bfloat16* wTap = wB + (size_t)tap * 8 * 8192;
#pragma unroll
        for (int s = 0; s < 8; ++s) {
            s8v af[7], bfr[4];
            static_for<0, 4>([&](auto NT) {
                bfr[NT.value] = *reinterpret_cast<const s8v*>(&wTap[(size_t)s * 8192 + bofs[NT.value]]);
            });
            static_for<0, 7>([&](auto MT) {
                af[MT.value] = *reinterpret_cast<const s8v*>(&bfh[rsel[MT.value] + s * 32 + qofs]);
            });
            __builtin_amdgcn_s_setprio(1);
            static_for<0, 7>([&](auto MT) {
                static_for<0, 4>([&](auto NT) {
                    acc[MT.value][NT.value] = __builtin_amdgcn_mfma_f32_16x16x32_bf16(
                        af[MT.value], bfr[NT.value], acc[MT.value][NT.value], 0, 0, 0);
                });
            });
            __builtin_amdgcn_s_setprio(0);
        }
    }

    // ---- phase 3: bias+relu+align GEMV; D row = MT*16 + hi*4 + RR -> (p, r=RR&1) ----
    const int hi = lane >> 4;
    float cb[4];
    static_for<0, 4>([&](auto NT) { cb[NT.value] = conv_b[wid * 64 + NT.value * 16 + l15]; });
    float pc[2][5] = {};
    static_for<0, 7>([&](auto MT) {
        static_for<0, 4>([&](auto RR) {
            constexpr int r = RR.value & 1;
            const int p = MT.value * 8 + hi * 2 + (RR.value >> 1);
            if (p < 49) {
                static_for<0, 4>([&](auto NT) {
                    const int co = wid * 64 + NT.value * 16 + l15;
                    const float4 w4 = aw4[p * 256 + co];
                    const float  w1 = aw1[p * 256 + co];
                    const float a = fmaxf(acc[MT.value][NT.value][RR.value] + cb[NT.value], 0.f);
                    pc[r][0] = fmaf(a, w4.x, pc[r][0]);
                    pc[r][1] = fmaf(a, w4.y, pc[r][1]);
                    pc[r][2] = fmaf(a, w4.z, pc[r][2]);
                    pc[r][3] = fmaf(a, w4.w, pc[r][3]);
                    pc[r][4] = fmaf(a, w1,   pc[r][4]);
                });
            }
        });
    });
    static_for<0, 2>([&](auto RI) {
        static_for<0, 5>([&](auto J) {
            float s = pc[RI.value][J.value];
#pragma unroll
            for (int off = 32; off; off >>= 1) s += __shfl_xor(s, off);
            pc[RI.value][J.value] = s;
        });
        if (lane == 0) {
            static_for<0, 5>([&](auto J) { red[RI.value * 20 + wid * 5 + J.value] = pc[RI.value][J.value]; });
        }
    });
    __syncthreads();

    // ---- phase 4: decode -> grid params (lanes 0,1 of wave 0) ----
    if (t < 2) {
        const int r = t;
        const int n = blk * 2 + r;
        float coarse[5];
        static_for<0, 5>([&](auto Jc) {
            constexpr int j = Jc.value;
            float s = red[r * 20 + j] + red[r * 20 + 5 + j] + red[r * 20 + 10 + j] +
                      red[r * 20 + 15 + j] + align_b[j];
            coarse[j] = fminf(fmaxf(s, -CLAMP_V), CLAMP_V);
        });
        const float x1r = proposals[n * 4 + 0], y1r = proposals[n * 4 + 1];
        const float x2r = proposals[n * 4 + 2], y2r = proposals[n * 4 + 3];
        const float w = x2r - x1r, h = y2r - y1r;
        const float w2 = w * expf(coarse[2]);
        const float h2 = h * expf(coarse[3]);
        const float ang = coarse[4];
        const float cth = cosf(ang), sth = sinf(ang);
        const float sx = w2 * (1.0f / OUT), sy = h2 * (1.0f / OUT);
        red[48 + r * 4 + 0] = sx * cth;
        red[48 + r * 4 + 1] = sy * sth;
        red[48 + r * 4 + 2] = sx * sth;
        red[48 + r * 4 + 3] = sy * cth;
    }
    __syncthreads();

    // ---- phase 5: grid_sample(zeros), vectorized x4: wave-uniform p, lane = 4 channels ----
#pragma unroll
    for (int r = 0; r < 2; ++r) {
        const float gA = red[48 + r * 4 + 0], gBv = red[48 + r * 4 + 1];
        const float gC = red[48 + r * 4 + 2], gD = red[48 + r * 4 + 3];
        __hip_bfloat16* ao = alignedOut + (size_t)(blk * 2 + r) * FD;
        const int c4 = lane * 4;
#pragma unroll 2
        for (int p = wid; p < P; p += 4) {             // wave-uniform bin
            const int pyi = p / 7, pxi = p % 7;
            const float xb = (2 * pxi + 1) * (1.0f / OUT) - 1.0f;
            const float yb = (2 * pyi + 1) * (1.0f / OUT) - 1.0f;
            const float gx = gA * xb - gBv * yb;
            const float gy = gC * xb + gD * yb;
            const float ix = ((gx + 1.0f) * OUT - 1.0f) * 0.5f;
            const float iy = ((gy + 1.0f) * OUT - 1.0f) * 0.5f;
            const float x0f = floorf(ix), y0f = floorf(iy);
            const int x0 = (int)x0f, y0 = (int)y0f;
            const float wx1 = ix - x0f, wy1 = iy - y0f;
            const float wx0 = 1.f - wx1, wy0 = 1.f - wy1;
            const float w00 = wy0 * wx0, w01 = wy0 * wx1, w10 = wy1 * wx0, w11 = wy1 * wx1;
            const bool vx0 = (unsigned)x0 < 7u, vx1 = (unsigned)(x0 + 1) < 7u;
            const bool vy0 = (unsigned)y0 < 7u, vy1 = (unsigned)(y0 + 1) < 7u;
            const int r00 = (vy0 && vx0) ? (y0 * 7 + x0) : 49;       // 2*49+r = zero row
            const int r01 = (vy0 && vx1) ? (y0 * 7 + x0 + 1) : 49;
            const int r10 = (vy1 && vx0) ? ((y0 + 1) * 7 + x0) : 49;
            const int r11 = (vy1 && vx1) ? ((y0 + 1) * 7 + x0 + 1) : 49;
            const s4v b00 = *reinterpret_cast<const s4v*>(&bfh[(2 * r00 + r) * LDB + c4]);
            const s4v b01 = *reinterpret_cast<const s4v*>(&bfh[(2 * r01 + r) * LDB + c4]);
            const s4v b10 = *reinterpret_cast<const s4v*>(&bfh[(2 * r10 + r) * LDB + c4]);
            const s4v b11 = *reinterpret_cast<const s4v*>(&bfh[(2 * r11 + r) * LDB + c4]);
            s4v o4;
            static_for<0, 4>([&](auto J) {
                constexpr int j = J.value;
                float v = w00 * __bfloat162float(__ushort_as_bfloat16((unsigned short)b00[j]))
                        + w01 * __bfloat162float(__ushort_as_bfloat16((unsigned short)b01[j]))
                        + w10 * __bfloat162float(__ushort_as_bfloat16((unsigned short)b10[j]))
                        + w11 * __bfloat162float(__ushort_as_bfloat16((unsigned short)b11[j]));
                o4[j] = (short)__bfloat16_as_ushort(__float2bfloat16(v));
            });
            *reinterpret_cast<s4v*>(&ao[p * 256 + c4]) = o4;
        }
    }
}

// ---- K3/K4: bf16 MFMA GEMM, BM=BN=BK=64, 4 blocks/CU target ----
template <int BM, int BN, int BK>
__global__ __launch_bounds__(256, 4) void k_gemm_bf16(
    const __hip_bfloat16* __restrict__ A, const __hip_bfloat16* __restrict__ Wt,
    const float* __restrict__ bias, float* __restrict__ CoutF,
    __hip_bfloat16* __restrict__ CoutH, int M, int Nn, int K, int relu) {
    constexpr int LD = BK + 8; // 72 halfwords
    __shared__ __align__(16) __hip_bfloat16 As[2][BM * LD];
    __shared__ __align__(16) __hip_bfloat16 Ws[2][BN * LD];
    const int ntb = Nn / BN;
    const int blkS = xcd_swz(blockIdx.x, gridDim.x);
    const int bx = blkS % ntb, by = blkS / ntb;
    const int t = threadIdx.x;
    const int lane = t & 63, wid = t >> 6;
    const int l15 = lane & 15;
    const int qofs = (lane >> 4) * 8;
    const int wm = wid >> 1, wn = wid & 1;

    const int ar = t >> 3, ak = (t & 7) * 8;
    const size_t aBase = (size_t)(by * BM) * K;
    const size_t bBase = (size_t)(bx * BN) * K;

    f32x4 acc[2][2] = {};

    const int steps = K / BK;
    {
        const s8v a0 = *reinterpret_cast<const s8v*>(&A[aBase + (size_t)ar * K + ak]);
        const s8v a1 = *reinterpret_cast<const s8v*>(&A[aBase + (size_t)(ar + 32) * K + ak]);
        const s8v b0 = *reinterpret_cast<const s8v*>(&Wt[bBase + (size_t)ar * K + ak]);
        const s8v b1 = *reinterpret_cast<const s8v*>(&Wt[bBase + (size_t)(ar + 32) * K + ak]);
        *reinterpret_cast<s8v*>(&As[0][ar * LD + ak]) = a0;
        *reinterpret_cast<s8v*>(&As[0][(ar + 32) * LD + ak]) = a1;
        *reinterpret_cast<s8v*>(&Ws[0][ar * LD + ak]) = b0;
        *reinterpret_cast<s8v*>(&Ws[0][(ar + 32) * LD + ak]) = b1;
    }
    __syncthreads();

    for (int s = 0; s < steps; ++s) {
        const int cur = s & 1;
        const bool pf = (s + 1 < steps);
        s8v a0, a1, b0, b1;
        if (pf) {
            const int k0 = (s + 1) * BK;
            a0 = *reinterpret_cast<const s8v*>(&A[aBase + (size_t)ar * K + k0 + ak]);
            a1 = *reinterpret_cast<const s8v*>(&A[aBase + (size_t)(ar + 32) * K + k0 + ak]);
            b0 = *reinterpret_cast<const s8v*>(&Wt[bBase + (size_t)ar * K + k0 + ak]);
            b1 = *reinterpret_cast<const s8v*>(&Wt[bBase + (size_t)(ar + 32) * K + k0 + ak]);
        }
        static_for<0, 2>([&](auto KH) {
            s8v afr[2], bfr[2];
            static_for<0, 2>([&](auto MT) {
                afr[MT.value] = *reinterpret_cast<const s8v*>(
                    &As[cur][(wm * 32 + MT.value * 16 + l15) * LD + KH.value * 32 + qofs]);
            });
            static_for<0, 2>([&](auto NT) {
                bfr[NT.value] = *reinterpret_cast<const s8v*>(
                    &Ws[cur][(wn * 32 + NT.value * 16 + l15) * LD + KH.value * 32 + qofs]);
            });
            static_for<0, 2>([&](auto MT) {
                static_for<0, 2>([&](auto NT) {
                    acc[MT.value][NT.value] = __builtin_amdgcn_mfma_f32_16x16x32_bf16(
                        afr[MT.value], bfr[NT.value], acc[MT.value][NT.value], 0, 0, 0);
                });
            });
        });
        if (pf) {
            __syncthreads();
            const int nxt = cur ^ 1;
            *reinterpret_cast<s8v*>(&As[nxt][ar * LD + ak]) = a0;
            *reinterpret_cast<s8v*>(&As[nxt][(ar + 32) * LD + ak]) = a1;
            *reinterpret_cast<s8v*>(&Ws[nxt][ar * LD + ak]) = b0;
            *reinterpret_cast<s8v*>(&Ws[nxt][(ar + 32) * LD + ak]) = b1;
            __syncthreads();
        }
    }

    static_for<0, 2>([&](auto MT) {
        static_for<0, 2>([&](auto NT) {
            const int col = bx * BN + wn * 32 + NT.value * 16 + l15;
            const float bv = bias[col];
            static_for<0, 4>([&](auto RR) {
                const int row = by * BM + wm * 32 + MT.value * 16 + (lane >> 4) * 4 + RR.value;
                float v = acc[MT.value][NT.value][RR.value] + bv;
                if (relu) v = fmaxf(v, 0.f);
                if (CoutF) CoutF[(size_t)row * Nn + col] = v;
                if (CoutH) CoutH[(size_t)row * Nn + col] = __float2bfloat16(v);
            });
        });
    });
}

// ---------------- K5: heads (cls/box GEMV + softmax + decode) ----------------
__global__ void k_heads(const float* __restrict__ r2, const float* __restrict__ cls_w,
                        const float* __restrict__ cls_b, const float* __restrict__ box_w,
                        const float* __restrict__ box_b, const float* __restrict__ proposals,
                        float* __restrict__ out) {
    const int n = blockIdx.x;
    const int t = threadIdx.x; // 64 lanes
    const float* r = r2 + (size_t)n * K1;
    float rv[16];
    static_for<0, 16>([&](auto Jc) { rv[Jc.value] = r[t + 64 * Jc.value]; });
    float s[21];
    static_for<0, 21>([&](auto Oc) {
        constexpr int o = Oc.value;
        const float* w = (o < 16) ? (cls_w + (size_t)o * K1) : (box_w + (size_t)(o - 16) * K1);
        float a = 0.f;
        static_for<0, 16>([&](auto Jc) { a = fmaf(rv[Jc.value], w[t + 64 * Jc.value], a); });
#pragma unroll
        for (int off = 32; off; off >>= 1) a += __shfl_xor(a, off);
        s[o] = a;
    });
    float logits[16];
    float m = -1e30f;
    static_for<0, 16>([&](auto Oc) {
        logits[Oc.value] = s[Oc.value] + cls_b[Oc.value];
        m = fmaxf(m, logits[Oc.value]);
    });
    float es = 0.f;
    static_for<0, 16>([&](auto Oc) {
        logits[Oc.value] = expf(logits[Oc.value] - m);
        es += logits[Oc.value];
    });
    const float inv = 1.0f / es;
    float fdelta[5];
    static_for<0, 5>([&](auto Jc) {
        fdelta[Jc.value] = fminf(fmaxf(s[16 + Jc.value] + box_b[Jc.value], -CLAMP_V), CLAMP_V);
    });
    const float x1r = proposals[n * 4 + 0], y1r = proposals[n * 4 + 1];
    const float x2r = proposals[n * 4 + 2], y2r = proposals[n * 4 + 3];
    const float cx = (x1r + x2r) * 0.5f, cy = (y1r + y2r) * 0.5f;
    const float w = x2r - x1r, h = y2r - y1r;
    float pred[5];
    pred[0] = cx + fdelta[0] * w;
    pred[1] = cy + fdelta[1] * h;
    pred[2] = w * expf(fdelta[2]);
    pred[3] = h * expf(fdelta[3]);
    pred[4] = fdelta[4];
    float* orow = out + (size_t)n * 21;
    static_for<0, 5>([&](auto Oc) {
        if (t == Oc.value) orow[Oc.value] = pred[Oc.value];
    });
    static_for<0, 16>([&](auto Oc) {
        if (t == 5 + Oc.value) orow[5 + Oc.value] = logits[Oc.value] * inv;
    });
}

extern "C" void kernel_launch(void* const* d_in, const int* in_sizes, int n_in,
                              void* d_out, int out_size, void* d_ws, size_t ws_size,
                              hipStream_t stream) {
    (void)in_sizes; (void)n_in; (void)out_size; (void)ws_size;
    const float* features  = (const float*)d_in[0];
    const float* proposals = (const float*)d_in[1];
    const int*   batch_idx = (const int*)d_in[2];
    const float* conv_w    = (const float*)d_in[3];
    const float* conv_b    = (const float*)d_in[4];
    const float* align_w   = (const float*)d_in[5];
    const float* align_b   = (const float*)d_in[6];
    const float* fc1_w     = (const float*)d_in[7];
    const float* fc1_b     = (const float*)d_in[8];
    const float* fc2_w     = (const float*)d_in[9];
    const float* fc2_b     = (const float*)d_in[10];
    const float* cls_w     = (const float*)d_in[11];
    const float* cls_b     = (const float*)d_in[12];
    const float* box_w     = (const float*)d_in[13];
    const float* box_b     = (const float*)d_in[14];
    float* out = (float*)d_out;

    float* ws    = (float*)d_ws;
    float* featT = ws;                           //  2,097,152 f
    float* r2    = featT + (size_t)B * HW * C;   //  2,097,152 f
    float4* aw4  = (float4*)(r2 + (size_t)N * K1);   // 49*256 float4
    float* aw1   = (float*)(aw4 + 49 * 256);         // 12,544 f
    __hip_bfloat16* alignedH = (__hip_bfloat16*)(aw1 + 49 * 256); // 25,690,112 h
    __hip_bfloat16* r1H   = alignedH + (size_t)N * FD;   //  2,097,152 h
    __hip_bfloat16* wB    = r1H + (size_t)N * K1;        //    589,824 h
    __hip_bfloat16* fc1B  = wB + 2304 * 256;             // 12,845,056 h
    __hip_bfloat16* fc2B  = fc1B + (size_t)K1 * FD;      //  1,048,576 h

    k_prep_all<<<6521, 256, 0, stream>>>(features, featT, conv_w, wB, align_w, aw4, aw1,
                                         fc1_w, fc1B, fc2_w, fc2B);
    k_roi_conv_grid<<<N / 2, 256, 0, stream>>>(featT, proposals, batch_idx, wB, conv_b,
                                               aw4, aw1, align_b, alignedH);
    k_gemm_bf16<64, 64, 64><<<(N / 64) * (K1 / 64), 256, 0, stream>>>(
        alignedH, fc1B, fc1_b, nullptr, r1H, N, K1, FD, 1);
    k_gemm_bf16<64, 64, 64><<<(N / 64) * (K1 / 64), 256, 0, stream>>>(
        r1H, fc2B, fc2_b, r2, nullptr, N, K1, K1, 1);
    k_heads<<<N, 64, 0, stream>>>(r2, cls_w, cls_b, box_w, box_b, proposals, out);
}